// Round 6
// baseline (410.984 us; speedup 1.0000x reference)
//
#include <hip/hip_runtime.h>

#define DEPTH 18
#define NN ((1 << DEPTH) - 1)   // 262143

typedef __attribute__((ext_vector_type(8))) short short8;
typedef __attribute__((ext_vector_type(4))) float f32x4;

__device__ __forceinline__ float sigm_(float x) { return 1.f / (1.f + __expf(-x)); }
__device__ __forceinline__ float tanh_(float x) { float e = __expf(2.f * x); return 1.f - 2.f / (e + 1.f); }
__device__ __forceinline__ unsigned short f2bf(float f) {
    union { float f; unsigned int u; } v; v.f = f;
    unsigned int r = (v.u + 0x7fffu + ((v.u >> 16) & 1u)) >> 16;
    return (unsigned short)r;
}
__device__ __forceinline__ float bf2f(unsigned short h) {
    union { unsigned int u; float f; } v; v.u = ((unsigned int)h) << 16; return v.f;
}
__device__ __forceinline__ uint4 bfadd8(uint4 a, uint4 b) {   // RNE bf16 pairwise add
    const unsigned short* pa = (const unsigned short*)&a;
    const unsigned short* pb = (const unsigned short*)&b;
    uint4 o; unsigned short* po = (unsigned short*)&o;
    #pragma unroll
    for (int i = 0; i < 8; ++i) po[i] = f2bf(bf2f(pa[i]) + bf2f(pb[i]));
    return o;
}

// ---------------------------------------------------------------------------
// Prep: emb table -> bf16; packed bf16 B matrix; transposed Wout.
// bpack layout: [chunk c (8)][col j (512)][k-local (32)], contiguous bf16.
//   chunks 0-3 (x side):  col j<384: Wiou[k][j], j>=384: Wf[k][j-384]
//   chunks 4-7 (h side):  col j<384: Uiou[k][j], j>=384: Uf[k][j-384]
// ---------------------------------------------------------------------------
__global__ void cvt_emb(const float* __restrict__ src, unsigned short* __restrict__ dst, int n4) {
    int i = blockIdx.x * 256 + threadIdx.x;
    if (i < n4) {
        float4 v = ((const float4*)src)[i];
        ushort4 o; o.x = f2bf(v.x); o.y = f2bf(v.y); o.z = f2bf(v.z); o.w = f2bf(v.w);
        ((ushort4*)dst)[i] = o;
    }
}

__global__ void build_bpack(const float* __restrict__ Wiou, const float* __restrict__ Uiou,
                            const float* __restrict__ Wf, const float* __restrict__ Uf,
                            unsigned short* __restrict__ pack) {
    int idx = blockIdx.x * 256 + threadIdx.x;      // 131072 total
    int c = idx >> 14, r = idx & 16383, j = r >> 5, kl = r & 31;
    int k2 = c * 32 + kl;                          // 0..255; <128 = x side
    float v;
    if (j < 384) v = (k2 < 128) ? Wiou[k2 * 384 + j] : Uiou[(k2 - 128) * 384 + j];
    else { int jf = j - 384; v = (k2 < 128) ? Wf[k2 * 128 + jf] : Uf[(k2 - 128) * 128 + jf]; }
    pack[idx] = f2bf(v);
}

__global__ void build_woutT(const float* __restrict__ Wout, float* __restrict__ woutT) {
    int i = blockIdx.x * 256 + threadIdx.x;        // 3 blocks -> 768, use 640
    if (i < 640) { int c = i >> 7, k = i & 127; woutT[c * 132 + k] = Wout[k * 5 + c]; }
}

// ---------------------------------------------------------------------------
// Big-level MFMA kernel: 32 nodes/block, 256 threads (4 waves), d >= 10.
// A_s regions: 0=emb, 1=h_sum, 2=h_l, 3=h_r; h_sum computed IN the staging
// phase (fused — no extra barrier / LDS round-trip).  Staging thread map
// m=t&31, seg=t>>5 makes all LDS writes bank-conflict-free.
// A elem (region r, node m, k) at r*4096 + (k>>3)*256 + m*8 + (k&7).
// B fragments read directly from global bpack (L2-resident, zero reuse/blk).
// Wave w owns output cols w*32..+31 for all 5 gates -> lane-local epilogue.
// NO register c-prefetch (R5 post-mortem: it cost a wave slot -> 2/SIMD).
// ---------------------------------------------------------------------------
template<int HC>
__global__ __launch_bounds__(256, 2) void tree_level_mfma(
    const int* __restrict__ xids, const int* __restrict__ msk,
    const unsigned short* __restrict__ embB, const unsigned short* __restrict__ bpack,
    const float* __restrict__ biou, const float* __restrict__ bfv,
    const float* __restrict__ woutT, const float* __restrict__ bout,
    unsigned short* __restrict__ hB, float* __restrict__ c_ws, float* __restrict__ outp,
    int s0)
{
    __shared__ __align__(16) unsigned short A_s[16384];   // 4 x 4096, 32 KB

    const int t  = threadIdx.x;
    const int g0 = s0 + blockIdx.x * 32;

    {   // ---- fused staging: emb + h_l + h_r + h_sum ----
        const int m = t & 31, seg = t >> 5;     // node, 16-elem segment
        const int g = g0 + m;
        const int ei = xids[g] * msk[g];
        const int j0 = seg * 2;                 // 8-elem group index
        const uint4* es = (const uint4*)(embB + (size_t)ei * 128 + seg * 16);
        uint4 e0 = es[0], e1 = es[1];
        *(uint4*)&A_s[j0 * 256 + m * 8]       = e0;
        *(uint4*)&A_s[(j0 + 1) * 256 + m * 8] = e1;
        if (HC) {
            const int gl = 2 * g + 1;
            const uint4* lp = (const uint4*)(hB + (size_t)gl * 128 + seg * 16);
            const uint4* rp = (const uint4*)(hB + (size_t)(gl + 1) * 128 + seg * 16);
            uint4 l0 = lp[0], l1 = lp[1];
            uint4 r0 = rp[0], r1 = rp[1];
            *(uint4*)&A_s[2 * 4096 + j0 * 256 + m * 8]       = l0;
            *(uint4*)&A_s[2 * 4096 + (j0 + 1) * 256 + m * 8] = l1;
            *(uint4*)&A_s[3 * 4096 + j0 * 256 + m * 8]       = r0;
            *(uint4*)&A_s[3 * 4096 + (j0 + 1) * 256 + m * 8] = r1;
            uint4 s0v = bfadd8(l0, r0), s1v = bfadd8(l1, r1);
            *(uint4*)&A_s[4096 + j0 * 256 + m * 8]       = s0v;
            *(uint4*)&A_s[4096 + (j0 + 1) * 256 + m * 8] = s1v;
        }
    }
    __syncthreads();

    const int lane = t & 63, w = t >> 6;
    const int ln = lane & 15, q = lane >> 4;

    const unsigned short* bp = bpack + ln * 32 + q * 8;     // + c*16384 + tile*512
    const unsigned short* ap = A_s + q * 256 + ln * 8;      // + r*4096 + cc*1024 + rt*128

#define BF(c, tile) (*(const short8*)(bp + (c) * 16384 + (tile) * 512))
#define AF(r, cc, rt) (*(const short8*)(ap + (r) * 4096 + (cc) * 1024 + (rt) * 128))
#define MM(acc, a, b) acc = __builtin_amdgcn_mfma_f32_16x16x32_bf16(a, b, acc, 0, 0, 0)

    f32x4 accI[2][2] = {}, accO[2][2] = {}, accU[2][2] = {}, accFl[2][2] = {}, accFr[2][2] = {};
    const int ti = 2 * w, to = 8 + 2 * w, tu = 16 + 2 * w, tf = 24 + 2 * w;

    #pragma unroll
    for (int c = 0; c < 4; ++c) {      // emb chunks
        short8 bI0 = BF(c, ti), bI1 = BF(c, ti + 1);
        short8 bO0 = BF(c, to), bO1 = BF(c, to + 1);
        short8 bU0 = BF(c, tu), bU1 = BF(c, tu + 1);
        short8 aE0 = AF(0, c, 0), aE1 = AF(0, c, 1);
        MM(accI[0][0], aE0, bI0); MM(accI[0][1], aE0, bI1);
        MM(accI[1][0], aE1, bI0); MM(accI[1][1], aE1, bI1);
        MM(accO[0][0], aE0, bO0); MM(accO[0][1], aE0, bO1);
        MM(accO[1][0], aE1, bO0); MM(accO[1][1], aE1, bO1);
        MM(accU[0][0], aE0, bU0); MM(accU[0][1], aE0, bU1);
        MM(accU[1][0], aE1, bU0); MM(accU[1][1], aE1, bU1);
        if (HC) {
            short8 bF0 = BF(c, tf), bF1 = BF(c, tf + 1);
            MM(accFl[0][0], aE0, bF0); MM(accFl[0][1], aE0, bF1);
            MM(accFl[1][0], aE1, bF0); MM(accFl[1][1], aE1, bF1);
        }
    }
    if (HC) {
        #pragma unroll
        for (int rt = 0; rt < 2; ++rt)
            #pragma unroll
            for (int jt = 0; jt < 2; ++jt)
                accFr[rt][jt] = accFl[rt][jt];      // fork shared x_f
        #pragma unroll
        for (int c = 0; c < 4; ++c) {  // h chunks (bpack chunk 4+c)
            short8 bI0 = BF(4 + c, ti), bI1 = BF(4 + c, ti + 1);
            short8 bO0 = BF(4 + c, to), bO1 = BF(4 + c, to + 1);
            short8 bU0 = BF(4 + c, tu), bU1 = BF(4 + c, tu + 1);
            short8 bF0 = BF(4 + c, tf), bF1 = BF(4 + c, tf + 1);
            short8 aH0 = AF(1, c, 0), aH1 = AF(1, c, 1);
            short8 aL0 = AF(2, c, 0), aL1 = AF(2, c, 1);
            short8 aR0 = AF(3, c, 0), aR1 = AF(3, c, 1);
            MM(accI[0][0], aH0, bI0); MM(accI[0][1], aH0, bI1);
            MM(accI[1][0], aH1, bI0); MM(accI[1][1], aH1, bI1);
            MM(accO[0][0], aH0, bO0); MM(accO[0][1], aH0, bO1);
            MM(accO[1][0], aH1, bO0); MM(accO[1][1], aH1, bO1);
            MM(accU[0][0], aH0, bU0); MM(accU[0][1], aH0, bU1);
            MM(accU[1][0], aH1, bU0); MM(accU[1][1], aH1, bU1);
            MM(accFl[0][0], aL0, bF0); MM(accFl[0][1], aL0, bF1);
            MM(accFl[1][0], aL1, bF0); MM(accFl[1][1], aL1, bF1);
            MM(accFr[0][0], aR0, bF0); MM(accFr[0][1], aR0, bF1);
            MM(accFr[1][0], aR1, bF0); MM(accFr[1][1], aR1, bF1);
        }
    }
#undef BF
#undef AF

    __syncthreads();                 // all A_s reads done; reuse as f32 h_s
    float* h_s = (float*)A_s;        // 32 x 136 f32 (17.4 KB <= 32 KB)

    #pragma unroll
    for (int rt = 0; rt < 2; ++rt) {
        #pragma unroll
        for (int jt = 0; jt < 2; ++jt) {
            const int col = w * 32 + jt * 16 + ln;
            const float bib = biou[col], bob = biou[128 + col], bub = biou[256 + col];
            const float bfb = bfv[col];
            #pragma unroll
            for (int r = 0; r < 4; ++r) {
                const int row = rt * 16 + q * 4 + r;
                const int g = g0 + row;
                const float iv = accI[rt][jt][r] + bib;
                const float ov = accO[rt][jt][r] + bob;
                const float uv = accU[rt][jt][r] + bub;
                float fc = 0.f;
                if (HC) {
                    const float cl = c_ws[(size_t)(2 * g + 1) * 128 + col];
                    const float cr = c_ws[(size_t)(2 * g + 2) * 128 + col];
                    const float fl = sigm_(accFl[rt][jt][r] + bfb);
                    const float fr = sigm_(accFr[rt][jt][r] + bfb);
                    fc = fl * cl + fr * cr;
                }
                const float cc = sigm_(iv) * tanh_(uv) + fc;
                const float hh = sigm_(ov) * tanh_(cc);
                c_ws[(size_t)g * 128 + col] = cc;
                hB[(size_t)g * 128 + col] = f2bf(hh);
                h_s[row * 136 + col] = hh;
            }
        }
    }
    __syncthreads();
    if (t < 160) {                   // output head: 32 nodes x 5 cols, f32
        const int n = t / 5, cc5 = t - 5 * n;
        float acc = bout[cc5];
        #pragma unroll 4
        for (int k4 = 0; k4 < 32; ++k4) {
            const float4 hv = *(const float4*)&h_s[n * 136 + k4 * 4];
            const float4 wv = *(const float4*)&woutT[cc5 * 132 + k4 * 4];
            acc += hv.x * wv.x + hv.y * wv.y + hv.z * wv.z + hv.w * wv.w;
        }
        outp[(size_t)(g0 + n) * 5 + cc5] = acc;
    }
}

// ---------------------------------------------------------------------------
// Subtree kernel: block b processes levels d = dTop..dBot for the subtree
// whose dBot-level root is node (2^dBot-1)+b.  dTop-dBot == 4 (16..1 nodes).
// 16-row MFMA tiles; h carried between mini-levels in A_s fragment layout;
// c carried in double-buffered LDS.  All levels here have children.
// A elem (region r, m, k) at r*2048 + (k>>5)*512 + (((k>>3)&3)*16 + m)*8 + (k&7)
// ---------------------------------------------------------------------------
#define MM(acc, a, b) acc = __builtin_amdgcn_mfma_f32_16x16x32_bf16(a, b, acc, 0, 0, 0)
__global__ __launch_bounds__(256) void tree_subtree(
    const int* __restrict__ xids, const int* __restrict__ msk,
    const unsigned short* __restrict__ embB, const unsigned short* __restrict__ bpack,
    const float* __restrict__ biou, const float* __restrict__ bfv,
    const float* __restrict__ Wout, const float* __restrict__ bout,
    unsigned short* __restrict__ hB, float* __restrict__ c_ws, float* __restrict__ outp,
    int dTop, int dBot)
{
    __shared__ __align__(16) unsigned short A_s[6144];    // 3 x 2048, 12 KB
    __shared__ __align__(16) float cbuf[2][16][128];      // 16 KB
    __shared__ __align__(16) float wout_s[640];

    const int t = threadIdx.x, b = blockIdx.x;
    const int lane = t & 63, w = t >> 6;
    const int ln = lane & 15, q = lane >> 4;

    if (t < 160) ((float4*)wout_s)[t] = ((const float4*)Wout)[t];

    const int col0 = w * 32 + ln, col1 = col0 + 16;
    const float bib0 = biou[col0], bob0 = biou[128 + col0], bub0 = biou[256 + col0], bfb0 = bfv[col0];
    const float bib1 = biou[col1], bob1 = biou[128 + col1], bub1 = biou[256 + col1], bfb1 = bfv[col1];

    const unsigned short* bp = bpack + ln * 32 + q * 8;
    const unsigned short* ap = A_s + (q * 16 + ln) * 8;
    const int ti = 2 * w, to = 8 + 2 * w, tu = 16 + 2 * w, tf = 24 + 2 * w;

    for (int d = dTop; d >= dBot; --d) {
        const int nd = 1 << (d - dBot);
        const int g0 = ((1 << d) - 1) + (b << (d - dBot));
        const int par = (dTop - d) & 1;

        if (t < 128) {   // stage emb (region 0), 16 rows (garbage rows >= nd ok)
            const int m = t >> 3, seg = t & 7;
            const int g = g0 + m;
            const int ei = xids[g] * msk[g];
            const uint4* es = (const uint4*)(embB + (size_t)ei * 128 + seg * 16);
            uint4 e0 = es[0], e1 = es[1];
            const int cc = seg >> 1, q0 = (seg & 1) * 2;
            *(uint4*)&A_s[cc * 512 + (q0 * 16 + m) * 8]       = e0;
            *(uint4*)&A_s[cc * 512 + ((q0 + 1) * 16 + m) * 8] = e1;
        }
        if (d == dTop) {   // stage 32 child h rows from global
            const int row = t >> 3, sg = t & 7;
            const int child = 2 * g0 + 1 + row;
            const uint4* hp = (const uint4*)(hB + (size_t)child * 128 + sg * 16);
            uint4 h0 = hp[0], h1 = hp[1];
            const int reg = 1 + (row & 1), mm = row >> 1;
            const int cc = sg >> 1, q0 = (sg & 1) * 2;
            *(uint4*)&A_s[reg * 2048 + cc * 512 + (q0 * 16 + mm) * 8]       = h0;
            *(uint4*)&A_s[reg * 2048 + cc * 512 + ((q0 + 1) * 16 + mm) * 8] = h1;
        }
        __syncthreads();

        f32x4 accI[2] = {}, accO[2] = {}, accU[2] = {}, accFl[2] = {}, accFr[2] = {};
#define BF1(c, tile) (*(const short8*)(bp + (c) * 16384 + (tile) * 512))
#define AF1(r, c) (*(const short8*)(ap + (r) * 2048 + (c) * 512))
        #pragma unroll
        for (int c = 0; c < 4; ++c) {
            short8 aE = AF1(0, c);
            MM(accI[0], aE, BF1(c, ti)); MM(accI[1], aE, BF1(c, ti + 1));
            MM(accO[0], aE, BF1(c, to)); MM(accO[1], aE, BF1(c, to + 1));
            MM(accU[0], aE, BF1(c, tu)); MM(accU[1], aE, BF1(c, tu + 1));
            MM(accFl[0], aE, BF1(c, tf)); MM(accFl[1], aE, BF1(c, tf + 1));
        }
        accFr[0] = accFl[0]; accFr[1] = accFl[1];
        #pragma unroll
        for (int c = 0; c < 4; ++c) {
            short8 aL = AF1(1, c), aR = AF1(2, c);
            short8 bI0 = BF1(4 + c, ti), bI1 = BF1(4 + c, ti + 1);
            short8 bO0 = BF1(4 + c, to), bO1 = BF1(4 + c, to + 1);
            short8 bU0 = BF1(4 + c, tu), bU1 = BF1(4 + c, tu + 1);
            short8 bF0 = BF1(4 + c, tf), bF1 = BF1(4 + c, tf + 1);
            MM(accI[0], aL, bI0); MM(accI[0], aR, bI0);
            MM(accI[1], aL, bI1); MM(accI[1], aR, bI1);
            MM(accO[0], aL, bO0); MM(accO[0], aR, bO0);
            MM(accO[1], aL, bO1); MM(accO[1], aR, bO1);
            MM(accU[0], aL, bU0); MM(accU[0], aR, bU0);
            MM(accU[1], aL, bU1); MM(accU[1], aR, bU1);
            MM(accFl[0], aL, bF0); MM(accFl[1], aL, bF1);
            MM(accFr[0], aR, bF0); MM(accFr[1], aR, bF1);
        }
#undef BF1
#undef AF1
        __syncthreads();   // k-loop reads done before epilogue overwrites A_s h

        #pragma unroll
        for (int jt = 0; jt < 2; ++jt) {
            const int col = jt ? col1 : col0;
            const float bib = jt ? bib1 : bib0, bob = jt ? bob1 : bob0;
            const float bub = jt ? bub1 : bub0, bfb = jt ? bfb1 : bfb0;
            const f32x4 aI = accI[jt], aO = accO[jt], aU = accU[jt];
            const f32x4 aFl = accFl[jt], aFr = accFr[jt];
            #pragma unroll
            for (int r = 0; r < 4; ++r) {
                const int row = q * 4 + r;
                const int g = g0 + row;
                float cl, cr;
                if (d == dTop) {
                    cl = c_ws[(size_t)(2 * g + 1) * 128 + col];
                    cr = c_ws[(size_t)(2 * g + 2) * 128 + col];
                } else {
                    cl = cbuf[1 - par][2 * row][col];
                    cr = cbuf[1 - par][2 * row + 1][col];
                }
                const float iv = aI[r] + bib;
                const float ov = aO[r] + bob;
                const float uv = aU[r] + bub;
                const float fl = sigm_(aFl[r] + bfb);
                const float fr = sigm_(aFr[r] + bfb);
                const float cc = sigm_(iv) * tanh_(uv) + fl * cl + fr * cr;
                const float hh = sigm_(ov) * tanh_(cc);
                cbuf[par][row][col] = cc;
                const unsigned short hb = f2bf(hh);
                const int reg = 1 + (row & 1), mm = row >> 1;
                A_s[reg * 2048 + (col >> 5) * 512 + ((((col >> 3) & 3) * 16) + mm) * 8 + (col & 7)] = hb;
                if (row < nd) {
                    c_ws[(size_t)g * 128 + col] = cc;
                    hB[(size_t)g * 128 + col] = hb;
                }
            }
        }
        __syncthreads();
        if (t < nd * 5) {            // output head for this level's nodes
            const int n = t / 5, cc5 = t - 5 * n;
            const int reg = 1 + (n & 1), mm = n >> 1;
            float acc = bout[cc5];
            #pragma unroll 8
            for (int k = 0; k < 128; ++k) {
                const float hv = bf2f(A_s[reg * 2048 + (k >> 5) * 512 + ((((k >> 3) & 3) * 16) + mm) * 8 + (k & 7)]);
                acc += hv * wout_s[k * 5 + cc5];
            }
            outp[(size_t)(g0 + n) * 5 + cc5] = acc;
        }
        __syncthreads();
    }
}
#undef MM

extern "C" void kernel_launch(void* const* d_in, const int* in_sizes, int n_in,
                              void* d_out, int out_size, void* d_ws, size_t ws_size,
                              hipStream_t stream)
{
    (void)in_sizes; (void)n_in; (void)out_size; (void)ws_size;
    const int*   xids = (const int*)d_in[0];
    const int*   msk  = (const int*)d_in[1];
    const float* emb  = (const float*)d_in[2];
    const float* Wiou = (const float*)d_in[3];
    const float* Uiou = (const float*)d_in[4];
    const float* biou = (const float*)d_in[5];
    const float* Wf   = (const float*)d_in[6];
    const float* Uf   = (const float*)d_in[7];
    const float* bfv  = (const float*)d_in[8];
    const float* Wout = (const float*)d_in[9];
    const float* bout = (const float*)d_in[10];
    float* outp = (float*)d_out;

    // workspace: embB (8.2MB) | bpack (0.26MB) | hB (67MB) | c_ws f32 (134MB) | woutT (2.6KB)
    unsigned short* embB  = (unsigned short*)d_ws;
    unsigned short* bpack = embB + (size_t)32000 * 128;
    unsigned short* hB    = bpack + 131072;
    float*          c_ws  = (float*)(hB + (size_t)NN * 128);
    float*          woutT = c_ws + (size_t)NN * 128;

    cvt_emb<<<dim3((32000 * 128 / 4 + 255) / 256), dim3(256), 0, stream>>>(emb, embB, 32000 * 128 / 4);
    build_bpack<<<dim3(131072 / 256), dim3(256), 0, stream>>>(Wiou, Uiou, Wf, Uf, bpack);
    build_woutT<<<dim3(3), dim3(256), 0, stream>>>(Wout, woutT);

    {   // leaf level d = 17
        const int d = DEPTH - 1, s0 = (1 << d) - 1;
        tree_level_mfma<0><<<dim3((1 << d) / 32), dim3(256), 0, stream>>>(
            xids, msk, embB, bpack, biou, bfv, woutT, bout, hB, c_ws, outp, s0);
    }
    for (int d = DEPTH - 2; d >= 10; --d) {
        const int s0 = (1 << d) - 1;
        tree_level_mfma<1><<<dim3((1 << d) / 32), dim3(256), 0, stream>>>(
            xids, msk, embB, bpack, biou, bfv, woutT, bout, hB, c_ws, outp, s0);
    }
    // levels 9..5: 32 subtree blocks; levels 4..0: 1 subtree block
    tree_subtree<<<dim3(32), dim3(256), 0, stream>>>(
        xids, msk, embB, bpack, biou, bfv, Wout, bout, hB, c_ws, outp, 9, 5);
    tree_subtree<<<dim3(1), dim3(256), 0, stream>>>(
        xids, msk, embB, bpack, biou, bfv, Wout, bout, hB, c_ws, outp, 4, 0);
}

// Round 7
// 405.954 us; speedup vs baseline: 1.0124x; 1.0124x over previous
//
#include <hip/hip_runtime.h>

#define DEPTH 18
#define NN ((1 << DEPTH) - 1)   // 262143

typedef __attribute__((ext_vector_type(8))) short short8;
typedef __attribute__((ext_vector_type(4))) float f32x4;

__device__ __forceinline__ float sigm_(float x) { return 1.f / (1.f + __expf(-x)); }
__device__ __forceinline__ float tanh_(float x) { float e = __expf(2.f * x); return 1.f - 2.f / (e + 1.f); }
__device__ __forceinline__ unsigned short f2bf(float f) {
    union { float f; unsigned int u; } v; v.f = f;
    unsigned int r = (v.u + 0x7fffu + ((v.u >> 16) & 1u)) >> 16;
    return (unsigned short)r;
}
__device__ __forceinline__ float bf2f(unsigned short h) {
    union { unsigned int u; float f; } v; v.u = ((unsigned int)h) << 16; return v.f;
}
__device__ __forceinline__ uint4 bfadd8(uint4 a, uint4 b) {   // RNE bf16 pairwise add
    const unsigned short* pa = (const unsigned short*)&a;
    const unsigned short* pb = (const unsigned short*)&b;
    uint4 o; unsigned short* po = (unsigned short*)&o;
    #pragma unroll
    for (int i = 0; i < 8; ++i) po[i] = f2bf(bf2f(pa[i]) + bf2f(pb[i]));
    return o;
}

// ---------------------------------------------------------------------------
// Prep: emb table -> bf16; packed bf16 B matrix; transposed Wout.
// bpack layout: [chunk c (8)][col j (512)][k-local (32)], contiguous bf16.
//   chunks 0-3 (x side):  col j<384: Wiou[k][j], j>=384: Wf[k][j-384]
//   chunks 4-7 (h side):  col j<384: Uiou[k][j], j>=384: Uf[k][j-384]
// ---------------------------------------------------------------------------
__global__ void cvt_emb(const float* __restrict__ src, unsigned short* __restrict__ dst, int n4) {
    int i = blockIdx.x * 256 + threadIdx.x;
    if (i < n4) {
        float4 v = ((const float4*)src)[i];
        ushort4 o; o.x = f2bf(v.x); o.y = f2bf(v.y); o.z = f2bf(v.z); o.w = f2bf(v.w);
        ((ushort4*)dst)[i] = o;
    }
}

__global__ void build_bpack(const float* __restrict__ Wiou, const float* __restrict__ Uiou,
                            const float* __restrict__ Wf, const float* __restrict__ Uf,
                            unsigned short* __restrict__ pack) {
    int idx = blockIdx.x * 256 + threadIdx.x;      // 131072 total
    int c = idx >> 14, r = idx & 16383, j = r >> 5, kl = r & 31;
    int k2 = c * 32 + kl;                          // 0..255; <128 = x side
    float v;
    if (j < 384) v = (k2 < 128) ? Wiou[k2 * 384 + j] : Uiou[(k2 - 128) * 384 + j];
    else { int jf = j - 384; v = (k2 < 128) ? Wf[k2 * 128 + jf] : Uf[(k2 - 128) * 128 + jf]; }
    pack[idx] = f2bf(v);
}

__global__ void build_woutT(const float* __restrict__ Wout, float* __restrict__ woutT) {
    int i = blockIdx.x * 256 + threadIdx.x;        // 3 blocks -> 768, use 640
    if (i < 640) { int c = i >> 7, k = i & 127; woutT[c * 132 + k] = Wout[k * 5 + c]; }
}

// ---------------------------------------------------------------------------
// Big-level MFMA kernel: 32 nodes/block, 256 threads (4 waves), d >= 10.
// A_s regions: 0=emb, 1=h_sum, 2=h_l, 3=h_r; h_sum fused into staging.
// PADDED fragment-major layout: elem (region r, node m, k) at
//   r*4224 + (k>>3)*264 + m*8 + (k&7)          (group stride 264, not 256)
// 264 elem = 528 B breaks the 512 B bank period: write bank slot becomes
// ((j+m)%8) -> uniform over the wave (conflict-free), fragment-read slot
// (ln+q)%8 -> also uniform.  Staging map m=t>>3, seg=t&7 keeps global reads
// COALESCED (8 lanes cover one 256 B row) — R6's map was scattered; that,
// not bank conflicts, was the staging cost (R6 post-mortem).
// B fragments read directly from global bpack (L2-resident, zero reuse/blk).
// Wave w owns output cols w*32..+31 for all 5 gates -> lane-local epilogue.
// No register c-prefetch (R5 post-mortem: cost a wave slot).
// ---------------------------------------------------------------------------
template<int HC>
__global__ __launch_bounds__(256, 2) void tree_level_mfma(
    const int* __restrict__ xids, const int* __restrict__ msk,
    const unsigned short* __restrict__ embB, const unsigned short* __restrict__ bpack,
    const float* __restrict__ biou, const float* __restrict__ bfv,
    const float* __restrict__ woutT, const float* __restrict__ bout,
    unsigned short* __restrict__ hB, float* __restrict__ c_ws, float* __restrict__ outp,
    int s0)
{
    __shared__ __align__(16) unsigned short A_s[16896];   // 4 x 4224, 33 KB

    const int t  = threadIdx.x;
    const int g0 = s0 + blockIdx.x * 32;

    {   // ---- fused staging: emb + h_l + h_r + h_sum (coalesced loads) ----
        const int m = t >> 3, seg = t & 7;      // node, 16-elem segment
        const int g = g0 + m;
        const int ei = xids[g] * msk[g];
        const int j0 = seg * 2;                 // 8-elem group index
        const uint4* es = (const uint4*)(embB + (size_t)ei * 128 + seg * 16);
        uint4 e0 = es[0], e1 = es[1];
        *(uint4*)&A_s[j0 * 264 + m * 8]       = e0;
        *(uint4*)&A_s[(j0 + 1) * 264 + m * 8] = e1;
        if (HC) {
            const int gl = 2 * g + 1;
            const uint4* lp = (const uint4*)(hB + (size_t)gl * 128 + seg * 16);
            const uint4* rp = (const uint4*)(hB + (size_t)(gl + 1) * 128 + seg * 16);
            uint4 l0 = lp[0], l1 = lp[1];
            uint4 r0 = rp[0], r1 = rp[1];
            *(uint4*)&A_s[2 * 4224 + j0 * 264 + m * 8]       = l0;
            *(uint4*)&A_s[2 * 4224 + (j0 + 1) * 264 + m * 8] = l1;
            *(uint4*)&A_s[3 * 4224 + j0 * 264 + m * 8]       = r0;
            *(uint4*)&A_s[3 * 4224 + (j0 + 1) * 264 + m * 8] = r1;
            uint4 s0v = bfadd8(l0, r0), s1v = bfadd8(l1, r1);
            *(uint4*)&A_s[4224 + j0 * 264 + m * 8]       = s0v;
            *(uint4*)&A_s[4224 + (j0 + 1) * 264 + m * 8] = s1v;
        }
    }
    __syncthreads();

    const int lane = t & 63, w = t >> 6;
    const int ln = lane & 15, q = lane >> 4;

    const unsigned short* bp = bpack + ln * 32 + q * 8;     // + c*16384 + tile*512
    const unsigned short* ap = A_s + q * 264 + ln * 8;      // + r*4224 + cc*1056 + rt*128

#define BF(c, tile) (*(const short8*)(bp + (c) * 16384 + (tile) * 512))
#define AF(r, cc, rt) (*(const short8*)(ap + (r) * 4224 + (cc) * 1056 + (rt) * 128))
#define MM(acc, a, b) acc = __builtin_amdgcn_mfma_f32_16x16x32_bf16(a, b, acc, 0, 0, 0)

    f32x4 accI[2][2] = {}, accO[2][2] = {}, accU[2][2] = {}, accFl[2][2] = {}, accFr[2][2] = {};
    const int ti = 2 * w, to = 8 + 2 * w, tu = 16 + 2 * w, tf = 24 + 2 * w;

    #pragma unroll
    for (int c = 0; c < 4; ++c) {      // emb chunks
        short8 bI0 = BF(c, ti), bI1 = BF(c, ti + 1);
        short8 bO0 = BF(c, to), bO1 = BF(c, to + 1);
        short8 bU0 = BF(c, tu), bU1 = BF(c, tu + 1);
        short8 aE0 = AF(0, c, 0), aE1 = AF(0, c, 1);
        MM(accI[0][0], aE0, bI0); MM(accI[0][1], aE0, bI1);
        MM(accI[1][0], aE1, bI0); MM(accI[1][1], aE1, bI1);
        MM(accO[0][0], aE0, bO0); MM(accO[0][1], aE0, bO1);
        MM(accO[1][0], aE1, bO0); MM(accO[1][1], aE1, bO1);
        MM(accU[0][0], aE0, bU0); MM(accU[0][1], aE0, bU1);
        MM(accU[1][0], aE1, bU0); MM(accU[1][1], aE1, bU1);
        if (HC) {
            short8 bF0 = BF(c, tf), bF1 = BF(c, tf + 1);
            MM(accFl[0][0], aE0, bF0); MM(accFl[0][1], aE0, bF1);
            MM(accFl[1][0], aE1, bF0); MM(accFl[1][1], aE1, bF1);
        }
    }
    if (HC) {
        #pragma unroll
        for (int rt = 0; rt < 2; ++rt)
            #pragma unroll
            for (int jt = 0; jt < 2; ++jt)
                accFr[rt][jt] = accFl[rt][jt];      // fork shared x_f
        #pragma unroll
        for (int c = 0; c < 4; ++c) {  // h chunks (bpack chunk 4+c)
            short8 bI0 = BF(4 + c, ti), bI1 = BF(4 + c, ti + 1);
            short8 bO0 = BF(4 + c, to), bO1 = BF(4 + c, to + 1);
            short8 bU0 = BF(4 + c, tu), bU1 = BF(4 + c, tu + 1);
            short8 bF0 = BF(4 + c, tf), bF1 = BF(4 + c, tf + 1);
            short8 aH0 = AF(1, c, 0), aH1 = AF(1, c, 1);
            short8 aL0 = AF(2, c, 0), aL1 = AF(2, c, 1);
            short8 aR0 = AF(3, c, 0), aR1 = AF(3, c, 1);
            MM(accI[0][0], aH0, bI0); MM(accI[0][1], aH0, bI1);
            MM(accI[1][0], aH1, bI0); MM(accI[1][1], aH1, bI1);
            MM(accO[0][0], aH0, bO0); MM(accO[0][1], aH0, bO1);
            MM(accO[1][0], aH1, bO0); MM(accO[1][1], aH1, bO1);
            MM(accU[0][0], aH0, bU0); MM(accU[0][1], aH0, bU1);
            MM(accU[1][0], aH1, bU0); MM(accU[1][1], aH1, bU1);
            MM(accFl[0][0], aL0, bF0); MM(accFl[0][1], aL0, bF1);
            MM(accFl[1][0], aL1, bF0); MM(accFl[1][1], aL1, bF1);
            MM(accFr[0][0], aR0, bF0); MM(accFr[0][1], aR0, bF1);
            MM(accFr[1][0], aR1, bF0); MM(accFr[1][1], aR1, bF1);
        }
    }
#undef BF
#undef AF

    __syncthreads();                 // all A_s reads done; reuse as f32 h_s
    float* h_s = (float*)A_s;        // 32 x 136 f32 (17.4 KB <= 33 KB)

    #pragma unroll
    for (int rt = 0; rt < 2; ++rt) {
        #pragma unroll
        for (int jt = 0; jt < 2; ++jt) {
            const int col = w * 32 + jt * 16 + ln;
            const float bib = biou[col], bob = biou[128 + col], bub = biou[256 + col];
            const float bfb = bfv[col];
            #pragma unroll
            for (int r = 0; r < 4; ++r) {
                const int row = rt * 16 + q * 4 + r;
                const int g = g0 + row;
                const float iv = accI[rt][jt][r] + bib;
                const float ov = accO[rt][jt][r] + bob;
                const float uv = accU[rt][jt][r] + bub;
                float fc = 0.f;
                if (HC) {
                    const float cl = c_ws[(size_t)(2 * g + 1) * 128 + col];
                    const float cr = c_ws[(size_t)(2 * g + 2) * 128 + col];
                    const float fl = sigm_(accFl[rt][jt][r] + bfb);
                    const float fr = sigm_(accFr[rt][jt][r] + bfb);
                    fc = fl * cl + fr * cr;
                }
                const float cc = sigm_(iv) * tanh_(uv) + fc;
                const float hh = sigm_(ov) * tanh_(cc);
                c_ws[(size_t)g * 128 + col] = cc;
                hB[(size_t)g * 128 + col] = f2bf(hh);
                h_s[row * 136 + col] = hh;
            }
        }
    }
    __syncthreads();
    if (t < 160) {                   // output head: 32 nodes x 5 cols, f32
        const int n = t / 5, cc5 = t - 5 * n;
        float acc = bout[cc5];
        #pragma unroll 4
        for (int k4 = 0; k4 < 32; ++k4) {
            const float4 hv = *(const float4*)&h_s[n * 136 + k4 * 4];
            const float4 wv = *(const float4*)&woutT[cc5 * 132 + k4 * 4];
            acc += hv.x * wv.x + hv.y * wv.y + hv.z * wv.z + hv.w * wv.w;
        }
        outp[(size_t)(g0 + n) * 5 + cc5] = acc;
    }
}

// ---------------------------------------------------------------------------
// Subtree kernel: block b processes levels d = dTop..dBot for the subtree
// whose dBot-level root is node (2^dBot-1)+b.  dTop-dBot == 4 (16..1 nodes).
// 16-row MFMA tiles; h carried between mini-levels in A_s fragment layout;
// c carried in double-buffered LDS.  All levels here have children.
// A elem (region r, m, k) at r*2048 + (k>>5)*512 + (((k>>3)&3)*16 + m)*8 + (k&7)
// ---------------------------------------------------------------------------
#define MM(acc, a, b) acc = __builtin_amdgcn_mfma_f32_16x16x32_bf16(a, b, acc, 0, 0, 0)
__global__ __launch_bounds__(256) void tree_subtree(
    const int* __restrict__ xids, const int* __restrict__ msk,
    const unsigned short* __restrict__ embB, const unsigned short* __restrict__ bpack,
    const float* __restrict__ biou, const float* __restrict__ bfv,
    const float* __restrict__ Wout, const float* __restrict__ bout,
    unsigned short* __restrict__ hB, float* __restrict__ c_ws, float* __restrict__ outp,
    int dTop, int dBot)
{
    __shared__ __align__(16) unsigned short A_s[6144];    // 3 x 2048, 12 KB
    __shared__ __align__(16) float cbuf[2][16][128];      // 16 KB
    __shared__ __align__(16) float wout_s[640];

    const int t = threadIdx.x, b = blockIdx.x;
    const int lane = t & 63, w = t >> 6;
    const int ln = lane & 15, q = lane >> 4;

    if (t < 160) ((float4*)wout_s)[t] = ((const float4*)Wout)[t];

    const int col0 = w * 32 + ln, col1 = col0 + 16;
    const float bib0 = biou[col0], bob0 = biou[128 + col0], bub0 = biou[256 + col0], bfb0 = bfv[col0];
    const float bib1 = biou[col1], bob1 = biou[128 + col1], bub1 = biou[256 + col1], bfb1 = bfv[col1];

    const unsigned short* bp = bpack + ln * 32 + q * 8;
    const unsigned short* ap = A_s + (q * 16 + ln) * 8;
    const int ti = 2 * w, to = 8 + 2 * w, tu = 16 + 2 * w, tf = 24 + 2 * w;

    for (int d = dTop; d >= dBot; --d) {
        const int nd = 1 << (d - dBot);
        const int g0 = ((1 << d) - 1) + (b << (d - dBot));
        const int par = (dTop - d) & 1;

        if (t < 128) {   // stage emb (region 0), 16 rows (garbage rows >= nd ok)
            const int m = t >> 3, seg = t & 7;
            const int g = g0 + m;
            const int ei = xids[g] * msk[g];
            const uint4* es = (const uint4*)(embB + (size_t)ei * 128 + seg * 16);
            uint4 e0 = es[0], e1 = es[1];
            const int cc = seg >> 1, q0 = (seg & 1) * 2;
            *(uint4*)&A_s[cc * 512 + (q0 * 16 + m) * 8]       = e0;
            *(uint4*)&A_s[cc * 512 + ((q0 + 1) * 16 + m) * 8] = e1;
        }
        if (d == dTop) {   // stage 32 child h rows from global
            const int row = t >> 3, sg = t & 7;
            const int child = 2 * g0 + 1 + row;
            const uint4* hp = (const uint4*)(hB + (size_t)child * 128 + sg * 16);
            uint4 h0 = hp[0], h1 = hp[1];
            const int reg = 1 + (row & 1), mm = row >> 1;
            const int cc = sg >> 1, q0 = (sg & 1) * 2;
            *(uint4*)&A_s[reg * 2048 + cc * 512 + (q0 * 16 + mm) * 8]       = h0;
            *(uint4*)&A_s[reg * 2048 + cc * 512 + ((q0 + 1) * 16 + mm) * 8] = h1;
        }
        __syncthreads();

        f32x4 accI[2] = {}, accO[2] = {}, accU[2] = {}, accFl[2] = {}, accFr[2] = {};
#define BF1(c, tile) (*(const short8*)(bp + (c) * 16384 + (tile) * 512))
#define AF1(r, c) (*(const short8*)(ap + (r) * 2048 + (c) * 512))
        #pragma unroll
        for (int c = 0; c < 4; ++c) {
            short8 aE = AF1(0, c);
            MM(accI[0], aE, BF1(c, ti)); MM(accI[1], aE, BF1(c, ti + 1));
            MM(accO[0], aE, BF1(c, to)); MM(accO[1], aE, BF1(c, to + 1));
            MM(accU[0], aE, BF1(c, tu)); MM(accU[1], aE, BF1(c, tu + 1));
            MM(accFl[0], aE, BF1(c, tf)); MM(accFl[1], aE, BF1(c, tf + 1));
        }
        accFr[0] = accFl[0]; accFr[1] = accFl[1];
        #pragma unroll
        for (int c = 0; c < 4; ++c) {
            short8 aL = AF1(1, c), aR = AF1(2, c);
            short8 bI0 = BF1(4 + c, ti), bI1 = BF1(4 + c, ti + 1);
            short8 bO0 = BF1(4 + c, to), bO1 = BF1(4 + c, to + 1);
            short8 bU0 = BF1(4 + c, tu), bU1 = BF1(4 + c, tu + 1);
            short8 bF0 = BF1(4 + c, tf), bF1 = BF1(4 + c, tf + 1);
            MM(accI[0], aL, bI0); MM(accI[0], aR, bI0);
            MM(accI[1], aL, bI1); MM(accI[1], aR, bI1);
            MM(accO[0], aL, bO0); MM(accO[0], aR, bO0);
            MM(accO[1], aL, bO1); MM(accO[1], aR, bO1);
            MM(accU[0], aL, bU0); MM(accU[0], aR, bU0);
            MM(accU[1], aL, bU1); MM(accU[1], aR, bU1);
            MM(accFl[0], aL, bF0); MM(accFl[1], aL, bF1);
            MM(accFr[0], aR, bF0); MM(accFr[1], aR, bF1);
        }
#undef BF1
#undef AF1
        __syncthreads();   // k-loop reads done before epilogue overwrites A_s h

        #pragma unroll
        for (int jt = 0; jt < 2; ++jt) {
            const int col = jt ? col1 : col0;
            const float bib = jt ? bib1 : bib0, bob = jt ? bob1 : bob0;
            const float bub = jt ? bub1 : bub0, bfb = jt ? bfb1 : bfb0;
            const f32x4 aI = accI[jt], aO = accO[jt], aU = accU[jt];
            const f32x4 aFl = accFl[jt], aFr = accFr[jt];
            #pragma unroll
            for (int r = 0; r < 4; ++r) {
                const int row = q * 4 + r;
                const int g = g0 + row;
                float cl, cr;
                if (d == dTop) {
                    cl = c_ws[(size_t)(2 * g + 1) * 128 + col];
                    cr = c_ws[(size_t)(2 * g + 2) * 128 + col];
                } else {
                    cl = cbuf[1 - par][2 * row][col];
                    cr = cbuf[1 - par][2 * row + 1][col];
                }
                const float iv = aI[r] + bib;
                const float ov = aO[r] + bob;
                const float uv = aU[r] + bub;
                const float fl = sigm_(aFl[r] + bfb);
                const float fr = sigm_(aFr[r] + bfb);
                const float cc = sigm_(iv) * tanh_(uv) + fl * cl + fr * cr;
                const float hh = sigm_(ov) * tanh_(cc);
                cbuf[par][row][col] = cc;
                const unsigned short hb = f2bf(hh);
                const int reg = 1 + (row & 1), mm = row >> 1;
                A_s[reg * 2048 + (col >> 5) * 512 + ((((col >> 3) & 3) * 16) + mm) * 8 + (col & 7)] = hb;
                if (row < nd) {
                    c_ws[(size_t)g * 128 + col] = cc;
                    hB[(size_t)g * 128 + col] = hb;
                }
            }
        }
        __syncthreads();
        if (t < nd * 5) {            // output head for this level's nodes
            const int n = t / 5, cc5 = t - 5 * n;
            const int reg = 1 + (n & 1), mm = n >> 1;
            float acc = bout[cc5];
            #pragma unroll 8
            for (int k = 0; k < 128; ++k) {
                const float hv = bf2f(A_s[reg * 2048 + (k >> 5) * 512 + ((((k >> 3) & 3) * 16) + mm) * 8 + (k & 7)]);
                acc += hv * wout_s[k * 5 + cc5];
            }
            outp[(size_t)(g0 + n) * 5 + cc5] = acc;
        }
        __syncthreads();
    }
}
#undef MM

extern "C" void kernel_launch(void* const* d_in, const int* in_sizes, int n_in,
                              void* d_out, int out_size, void* d_ws, size_t ws_size,
                              hipStream_t stream)
{
    (void)in_sizes; (void)n_in; (void)out_size; (void)ws_size;
    const int*   xids = (const int*)d_in[0];
    const int*   msk  = (const int*)d_in[1];
    const float* emb  = (const float*)d_in[2];
    const float* Wiou = (const float*)d_in[3];
    const float* Uiou = (const float*)d_in[4];
    const float* biou = (const float*)d_in[5];
    const float* Wf   = (const float*)d_in[6];
    const float* Uf   = (const float*)d_in[7];
    const float* bfv  = (const float*)d_in[8];
    const float* Wout = (const float*)d_in[9];
    const float* bout = (const float*)d_in[10];
    float* outp = (float*)d_out;

    // workspace: embB (8.2MB) | bpack (0.26MB) | hB (67MB) | c_ws f32 (134MB) | woutT (2.6KB)
    unsigned short* embB  = (unsigned short*)d_ws;
    unsigned short* bpack = embB + (size_t)32000 * 128;
    unsigned short* hB    = bpack + 131072;
    float*          c_ws  = (float*)(hB + (size_t)NN * 128);
    float*          woutT = c_ws + (size_t)NN * 128;

    cvt_emb<<<dim3((32000 * 128 / 4 + 255) / 256), dim3(256), 0, stream>>>(emb, embB, 32000 * 128 / 4);
    build_bpack<<<dim3(131072 / 256), dim3(256), 0, stream>>>(Wiou, Uiou, Wf, Uf, bpack);
    build_woutT<<<dim3(3), dim3(256), 0, stream>>>(Wout, woutT);

    {   // leaf level d = 17
        const int d = DEPTH - 1, s0 = (1 << d) - 1;
        tree_level_mfma<0><<<dim3((1 << d) / 32), dim3(256), 0, stream>>>(
            xids, msk, embB, bpack, biou, bfv, woutT, bout, hB, c_ws, outp, s0);
    }
    for (int d = DEPTH - 2; d >= 10; --d) {
        const int s0 = (1 << d) - 1;
        tree_level_mfma<1><<<dim3((1 << d) / 32), dim3(256), 0, stream>>>(
            xids, msk, embB, bpack, biou, bfv, woutT, bout, hB, c_ws, outp, s0);
    }
    // levels 9..5: 32 subtree blocks; levels 4..0: 1 subtree block
    tree_subtree<<<dim3(32), dim3(256), 0, stream>>>(
        xids, msk, embB, bpack, biou, bfv, Wout, bout, hB, c_ws, outp, 9, 5);
    tree_subtree<<<dim3(1), dim3(256), 0, stream>>>(
        xids, msk, embB, bpack, biou, bfv, Wout, bout, hB, c_ws, outp, 4, 0);
}